// Round 2
// baseline (197.989 us; speedup 1.0000x reference)
//
#include <hip/hip_runtime.h>

// DEC Student-t soft assignment, ALPHA=1 -> q_ij = 1/(1+d2_ij), row-normalized.
// d2 = ||h||^2 + ||c||^2 - 2 h.c ; cross term via bf16 MFMA (error ~3e-7 abs on q,
// threshold 2.5e-5), h_sq/c_sq exact fp32.
//
// R1 -> R2: T2 XOR-swizzle on the LDS tiles. Old layout had 8-way bank
// conflicts on every ds_read_b128 (row stride 64 B = 16 dwords -> bank-quad
// = {hi, 4+hi} only). Swizzle granule g=4r+hi -> g^((g>>3)&7) spreads each
// 16-lane group across all 8 bank-quads (2 lanes each = free). LDS dest of
// global_load_lds stays linear; the per-lane GLOBAL source is pre-permuted
// by the same involution (rule #21: both-sides-or-neither).

typedef unsigned short u16;
typedef __attribute__((ext_vector_type(8))) short bf16x8;  // 8 bf16 = 4 VGPRs
typedef __attribute__((ext_vector_type(4))) float f32x4;

#define N_ROWS 32768
#define K_CENT 1000
#define KP     1024   // padded centroid count
#define DDIM   1024

__device__ __forceinline__ u16 f2bf(float x) {
  unsigned u = __float_as_uint(x);
  u += 0x7fffu + ((u >> 16) & 1u);   // round-to-nearest-even
  return (u16)(u >> 16);
}

// async global->LDS, 16 B per lane. LDS dest is wave-uniform base; HW adds lane*16.
__device__ __forceinline__ void gload_lds16(const u16* g, u16* s) {
  __builtin_amdgcn_global_load_lds((__attribute__((address_space(1))) void*)g,
                                   (__attribute__((address_space(3))) void*)s,
                                   16, 0, 0);
}

// ---------------- prep kernels ----------------

__global__ __launch_bounds__(256) void prep_h(const float* __restrict__ h,
                                              u16* __restrict__ hb,
                                              float* __restrict__ hsq,
                                              float* __restrict__ rowsum) {
  const int row = blockIdx.x;
  const int t = threadIdx.x;
  const float4 v = reinterpret_cast<const float4*>(h + (size_t)row * DDIM)[t];
  ushort4 b;
  b.x = f2bf(v.x); b.y = f2bf(v.y); b.z = f2bf(v.z); b.w = f2bf(v.w);
  reinterpret_cast<ushort4*>(hb + (size_t)row * DDIM)[t] = b;
  float ss = v.x * v.x + v.y * v.y + v.z * v.z + v.w * v.w;
#pragma unroll
  for (int m = 1; m < 64; m <<= 1) ss += __shfl_xor(ss, m);
  __shared__ float sbuf[4];
  if ((t & 63) == 0) sbuf[t >> 6] = ss;
  __syncthreads();
  if (t == 0) {
    hsq[row] = sbuf[0] + sbuf[1] + sbuf[2] + sbuf[3];
    rowsum[row] = 0.0f;
  }
}

__global__ __launch_bounds__(256) void prep_c(const float* __restrict__ c,
                                              u16* __restrict__ cb,
                                              float* __restrict__ csq) {
  const int row = blockIdx.x;
  const int t = threadIdx.x;
  if (row < K_CENT) {
    const float4 v = reinterpret_cast<const float4*>(c + (size_t)row * DDIM)[t];
    ushort4 b;
    b.x = f2bf(v.x); b.y = f2bf(v.y); b.z = f2bf(v.z); b.w = f2bf(v.w);
    reinterpret_cast<ushort4*>(cb + (size_t)row * DDIM)[t] = b;
    float ss = v.x * v.x + v.y * v.y + v.z * v.z + v.w * v.w;
#pragma unroll
    for (int m = 1; m < 64; m <<= 1) ss += __shfl_xor(ss, m);
    __shared__ float sbuf[4];
    if ((t & 63) == 0) sbuf[t >> 6] = ss;
    __syncthreads();
    if (t == 0) csq[row] = sbuf[0] + sbuf[1] + sbuf[2] + sbuf[3];
  } else {
    // pad rows: zero bf16 (cross=0), huge c_sq -> q = 1/(1+1e30) ~ 1e-30 ~ 0
    ushort4 z; z.x = z.y = z.z = z.w = 0;
    reinterpret_cast<ushort4*>(cb + (size_t)row * DDIM)[t] = z;
    if (t == 0) csq[row] = 1e30f;
  }
}

// ---------------- main GEMM + q epilogue ----------------

// Tile = 128 rows x 32 k bf16 = 512 granules of 16 B. Logical granule
// g = 4*row + hi (hi = 16B chunk within row). Stored at p = g ^ ((g>>3)&7)
// (involution; p>>3 == g>>3 so inverse is the same map).
__device__ __forceinline__ void stage_tile(const u16* __restrict__ gA,
                                           const u16* __restrict__ gB,
                                           u16* sA, u16* sB,
                                           int w, int l, int k0) {
  // 8 chunks of 1 KB (64 granules); wave w stages chunks {w, w+4}.
#pragma unroll
  for (int i = 0; i < 2; ++i) {
    const int c = w + i * 4;
    const int p = c * 64 + l;            // linear granule this lane writes
    const int g = p ^ ((p >> 3) & 7);    // logical granule whose data belongs at p
    const int roff = g >> 2;
    const int koff = (g & 3) * 8;
    const size_t go = (size_t)roff * DDIM + k0 + koff;
    gload_lds16(gA + go, sA + c * 512);  // uniform base; HW adds l*16 B
    gload_lds16(gB + go, sB + c * 512);
  }
}

__global__ __launch_bounds__(256) void gemm_q(const u16* __restrict__ hb,
                                              const u16* __restrict__ cb,
                                              const float* __restrict__ hsq,
                                              const float* __restrict__ csq,
                                              float* __restrict__ out,
                                              float* __restrict__ rowsum) {
  __shared__ u16 As[2][128 * 32];
  __shared__ u16 Bs[2][128 * 32];

  const int bid = blockIdx.x;
  // XCD swizzle (2048 % 8 == 0): each XCD gets 32 consecutive row panels x 8 col blocks
  const int swz = ((bid & 7) << 8) | (bid >> 3);
  const int bcol = swz & 7;    // 8 column blocks of 128 (KP=1024)
  const int brow = swz >> 3;   // 256 row panels of 128

  const int t = threadIdx.x;
  const int w = t >> 6;
  const int l = t & 63;
  const int wr = w >> 1;       // wave row (0..1), 64 rows each
  const int wc = w & 1;        // wave col (0..1), 64 cols each

  const u16* gA = hb + (size_t)brow * 128 * DDIM;
  const u16* gB = cb + (size_t)bcol * 128 * DDIM;

  f32x4 acc[4][4] = {};

  stage_tile(gA, gB, &As[0][0], &Bs[0][0], w, l, 0);

  const int hi = l >> 4;
  const int rA0 = wr * 64 + (l & 15);
  const int rB0 = wc * 64 + (l & 15);

  const int NT = DDIM / 32;
  for (int kt = 0; kt < NT; ++kt) {
    const int cur = kt & 1;
    __syncthreads();  // stage(kt) complete (vmcnt drain) + prior reads done
    if (kt + 1 < NT)
      stage_tile(gA, gB, &As[cur ^ 1][0], &Bs[cur ^ 1][0], w, l, (kt + 1) * 32);

    bf16x8 aF[4], bF[4];
#pragma unroll
    for (int m = 0; m < 4; ++m) {
      const int ga = ((rA0 + m * 16) << 2) | hi;
      const int gb = ((rB0 + m * 16) << 2) | hi;
      aF[m] = *(const bf16x8*)&As[cur][(ga ^ ((ga >> 3) & 7)) << 3];
      bF[m] = *(const bf16x8*)&Bs[cur][(gb ^ ((gb >> 3) & 7)) << 3];
    }
#pragma unroll
    for (int m = 0; m < 4; ++m)
#pragma unroll
      for (int n = 0; n < 4; ++n)
        acc[m][n] = __builtin_amdgcn_mfma_f32_16x16x32_bf16(aF[m], bF[n], acc[m][n], 0, 0, 0);
  }

  // Epilogue: C/D layout (16x16x32): col = l&15, row = (l>>4)*4 + reg
  const int gi0 = brow * 128 + wr * 64;
  const int gj0 = bcol * 128 + wc * 64;
  const int lr = (l >> 4) << 2;
  const int lc = l & 15;

#pragma unroll
  for (int m = 0; m < 4; ++m) {
    float hs[4];
#pragma unroll
    for (int r = 0; r < 4; ++r) hs[r] = hsq[gi0 + m * 16 + lr + r];
    float rs[4] = {0.f, 0.f, 0.f, 0.f};
#pragma unroll
    for (int n = 0; n < 4; ++n) {
      const int gj = gj0 + n * 16 + lc;
      const float cs = csq[gj];
#pragma unroll
      for (int r = 0; r < 4; ++r) {
        float d2 = hs[r] + cs - 2.0f * acc[m][n][r];
        d2 = fmaxf(d2, 0.0f);
        const float qv = 1.0f / (1.0f + d2);
        rs[r] += qv;
        if (gj < K_CENT)
          out[(size_t)(gi0 + m * 16 + lr + r) * K_CENT + gj] = qv;
      }
    }
#pragma unroll
    for (int r = 0; r < 4; ++r) {
      float v = rs[r];
      v += __shfl_xor(v, 1);
      v += __shfl_xor(v, 2);
      v += __shfl_xor(v, 4);
      v += __shfl_xor(v, 8);
      if (lc == 0) atomicAdd(&rowsum[gi0 + m * 16 + lr + r], v);
    }
  }
}

// ---------------- normalization ----------------

__global__ __launch_bounds__(256) void norm_k(float* __restrict__ out,
                                              const float* __restrict__ rowsum) {
  const int row = blockIdx.x;
  const int t = threadIdx.x;
  if (t < 250) {  // 1000 floats = 250 float4 per row (4000 B, 16B-aligned)
    const float inv = 1.0f / rowsum[row];
    float4* p = reinterpret_cast<float4*>(out) + (size_t)row * 250 + t;
    float4 v = *p;
    v.x *= inv; v.y *= inv; v.z *= inv; v.w *= inv;
    *p = v;
  }
}

// ---------------- launch ----------------

extern "C" void kernel_launch(void* const* d_in, const int* in_sizes, int n_in,
                              void* d_out, int out_size, void* d_ws, size_t ws_size,
                              hipStream_t stream) {
  const float* h   = (const float*)d_in[0];
  const float* cen = (const float*)d_in[1];
  float* out = (float*)d_out;
  char* ws = (char*)d_ws;

  // ws layout (66.3 MB total)
  u16*   cb     = (u16*)(ws);                           // 1024*1024*2   = 2 MB
  u16*   hb     = (u16*)(ws + 2097152);                 // 32768*1024*2  = 64 MB
  float* hsq    = (float*)(ws + 2097152 + 67108864);    // 128 KB
  float* csq    = (float*)(ws + 2097152 + 67108864 + 131072);   // 4 KB
  float* rowsum = (float*)(ws + 2097152 + 67108864 + 131072 + 4096); // 128 KB

  prep_c<<<KP, 256, 0, stream>>>(cen, cb, csq);
  prep_h<<<N_ROWS, 256, 0, stream>>>(h, hb, hsq, rowsum);
  gemm_q<<<(N_ROWS / 128) * (KP / 128), 256, 0, stream>>>(hb, cb, hsq, csq, out, rowsum);
  norm_k<<<N_ROWS, 256, 0, stream>>>(out, rowsum);
}

// Round 3
// 175.358 us; speedup vs baseline: 1.1291x; 1.1291x over previous
//
#include <hip/hip_runtime.h>

// DEC Student-t soft assignment, ALPHA=1 -> q_ij = 1/(1+d2_ij), row-normalized.
// d2 = ||h||^2 + ||c||^2 - 2 h.c ; cross term via bf16 MFMA, h_sq/c_sq exact fp32.
//
// R2 -> R3: 2-phase 128^2 double-buffer (vmcnt(0) drain each K-step = 72%-class
// structural stall, MfmaUtil 18.5%) replaced by 256^2 tile, BK=32, ring-4 LDS
// slots (128 KiB), counted vmcnt(8) per K-tile (T4 - never drain to 0 in main
// loop), one raw s_barrier per K-tile, 2 MFMA clusters of 16 per tile with
// setprio (T5), stage-issues interleaved between clusters (T3-lite).
// Granule swizzle p ^ ((p>>3)&7) (T2, verified 0 conflicts in R2) on both the
// pre-swizzled global source and the ds_read addresses.

typedef unsigned short u16;
typedef __attribute__((ext_vector_type(8))) short bf16x8;  // 8 bf16 = 4 VGPRs
typedef __attribute__((ext_vector_type(4))) float f32x4;

#define N_ROWS 32768
#define K_CENT 1000
#define KP     1024   // padded centroid count
#define DDIM   1024
#define NT     32     // K-tiles of BK=32

__device__ __forceinline__ u16 f2bf(float x) {
  unsigned u = __float_as_uint(x);
  u += 0x7fffu + ((u >> 16) & 1u);   // round-to-nearest-even
  return (u16)(u >> 16);
}

// async global->LDS, 16 B per lane. LDS dest is wave-uniform base; HW adds lane*16.
__device__ __forceinline__ void gload_lds16(const u16* g, u16* s) {
  __builtin_amdgcn_global_load_lds((__attribute__((address_space(1))) void*)g,
                                   (__attribute__((address_space(3))) void*)s,
                                   16, 0, 0);
}

// ---------------- prep kernels ----------------

__global__ __launch_bounds__(256) void prep_h(const float* __restrict__ h,
                                              u16* __restrict__ hb,
                                              float* __restrict__ hsq,
                                              float* __restrict__ rowsum) {
  const int row = blockIdx.x;
  const int t = threadIdx.x;
  const float4 v = reinterpret_cast<const float4*>(h + (size_t)row * DDIM)[t];
  ushort4 b;
  b.x = f2bf(v.x); b.y = f2bf(v.y); b.z = f2bf(v.z); b.w = f2bf(v.w);
  reinterpret_cast<ushort4*>(hb + (size_t)row * DDIM)[t] = b;
  float ss = v.x * v.x + v.y * v.y + v.z * v.z + v.w * v.w;
#pragma unroll
  for (int m = 1; m < 64; m <<= 1) ss += __shfl_xor(ss, m);
  __shared__ float sbuf[4];
  if ((t & 63) == 0) sbuf[t >> 6] = ss;
  __syncthreads();
  if (t == 0) {
    hsq[row] = sbuf[0] + sbuf[1] + sbuf[2] + sbuf[3];
    rowsum[row] = 0.0f;
  }
}

__global__ __launch_bounds__(256) void prep_c(const float* __restrict__ c,
                                              u16* __restrict__ cb,
                                              float* __restrict__ csq) {
  const int row = blockIdx.x;
  const int t = threadIdx.x;
  if (row < K_CENT) {
    const float4 v = reinterpret_cast<const float4*>(c + (size_t)row * DDIM)[t];
    ushort4 b;
    b.x = f2bf(v.x); b.y = f2bf(v.y); b.z = f2bf(v.z); b.w = f2bf(v.w);
    reinterpret_cast<ushort4*>(cb + (size_t)row * DDIM)[t] = b;
    float ss = v.x * v.x + v.y * v.y + v.z * v.z + v.w * v.w;
#pragma unroll
    for (int m = 1; m < 64; m <<= 1) ss += __shfl_xor(ss, m);
    __shared__ float sbuf[4];
    if ((t & 63) == 0) sbuf[t >> 6] = ss;
    __syncthreads();
    if (t == 0) csq[row] = sbuf[0] + sbuf[1] + sbuf[2] + sbuf[3];
  } else {
    ushort4 z; z.x = z.y = z.z = z.w = 0;
    reinterpret_cast<ushort4*>(cb + (size_t)row * DDIM)[t] = z;
    if (t == 0) csq[row] = 1e30f;  // pad rows: q ~ 1/(1+1e30) ~ 0
  }
}

// ---------------- main GEMM + q epilogue ----------------
// Tile 256 rows x 32 k = 1024 granules of 16 B per matrix per slot.
// Logical granule g = 4*row + j (j = 16B chunk in row). Stored at
// p = g ^ ((g>>3)&7) (involution, bank-quad balanced: 2 lanes/quad per
// 16-lane group -> conflict-free, verified R2).

__device__ __forceinline__ void stageA(const u16* __restrict__ gA, u16* sA,
                                       int tid, int t) {
#pragma unroll
  for (int i = 0; i < 2; ++i) {
    const int p = tid + i * 512;           // linear granule written
    const int g = p ^ ((p >> 3) & 7);      // logical granule fetched
    gload_lds16(gA + (size_t)(g >> 2) * DDIM + t * 32 + (g & 3) * 8,
                sA + (((tid & ~63) + i * 512) << 3));
  }
}
__device__ __forceinline__ void stageB(const u16* __restrict__ gB, u16* sB,
                                       int tid, int t) {
#pragma unroll
  for (int i = 0; i < 2; ++i) {
    const int p = tid + i * 512;
    const int g = p ^ ((p >> 3) & 7);
    gload_lds16(gB + (size_t)(g >> 2) * DDIM + t * 32 + (g & 3) * 8,
                sB + (((tid & ~63) + i * 512) << 3));
  }
}

__global__ __launch_bounds__(512, 2) void gemm_q(const u16* __restrict__ hb,
                                                 const u16* __restrict__ cb,
                                                 const float* __restrict__ hsq,
                                                 const float* __restrict__ csq,
                                                 float* __restrict__ out,
                                                 float* __restrict__ rowsum) {
  __shared__ u16 As[4][8192];  // 4 ring slots x (256x32) bf16 = 64 KB
  __shared__ u16 Bs[4][8192];  // 64 KB

  const int bid = blockIdx.x;
  // XCD swizzle: 512 blocks, 8 XCDs -> 64 consecutive per XCD (bcol fastest).
  const int swz = ((bid & 7) << 6) | (bid >> 3);
  const int bcol = swz & 3;    // 4 col panels of 256 (KP=1024)
  const int brow = swz >> 2;   // 128 row panels of 256

  const int tid = threadIdx.x;
  const int w = tid >> 6;
  const int l = tid & 63;
  const int wm = w >> 2;       // 0..1 : 128-row half
  const int wn = w & 3;        // 0..3 : 64-col slice

  const u16* gA = hb + (size_t)brow * 256 * DDIM;
  const u16* gB = cb + (size_t)bcol * 256 * DDIM;

  // prologue: prefetch tiles 0..2 into slots 0..2 (12 loads/thread)
  stageA(gA, As[0], tid, 0); stageB(gB, Bs[0], tid, 0);
  stageA(gA, As[1], tid, 1); stageB(gB, Bs[1], tid, 1);
  stageA(gA, As[2], tid, 2); stageB(gB, Bs[2], tid, 2);

  // precomputed swizzled frag offsets (u16 elems, slot-relative)
  int aOff[8], bOff[4];
#pragma unroll
  for (int m = 0; m < 8; ++m) {
    const int row = wm * 128 + m * 16 + (l & 15);
    const int g = (row << 2) | (l >> 4);
    aOff[m] = (g ^ ((g >> 3) & 7)) << 3;
  }
#pragma unroll
  for (int n = 0; n < 4; ++n) {
    const int row = wn * 64 + n * 16 + (l & 15);
    const int g = (row << 2) | (l >> 4);
    bOff[n] = (g ^ ((g >> 3) & 7)) << 3;
  }

  f32x4 acc[8][4] = {};

  // Per K-tile: vmcnt(VM) -> barrier -> [8 ds_read | stageA(t+3) | 16 MFMA]
  //                                  -> [4 ds_read | stageB(t+3) | 16 MFMA]
  // VM=8: tiles t+1,t+2 in flight (4 loads each). Tail: 4 then 0.
#define KTILE_BODY(T, VM)                                                      \
  {                                                                            \
    const int s_ = (T) & 3, ns_ = ((T) + 3) & 3;                               \
    asm volatile("s_waitcnt vmcnt(" #VM ")" ::: "memory");                     \
    __builtin_amdgcn_s_barrier();                                              \
    __builtin_amdgcn_sched_barrier(0);                                         \
    const u16* SA_ = As[s_]; const u16* SB_ = Bs[s_];                          \
    bf16x8 aF[4], bF[4];                                                       \
    _Pragma("unroll") for (int n = 0; n < 4; ++n)                              \
        bF[n] = *(const bf16x8*)(SB_ + bOff[n]);                               \
    _Pragma("unroll") for (int m = 0; m < 4; ++m)                              \
        aF[m] = *(const bf16x8*)(SA_ + aOff[m]);                               \
    if ((T) + 3 < NT) stageA(gA, As[ns_], tid, (T) + 3);                       \
    __builtin_amdgcn_s_setprio(1);                                             \
    _Pragma("unroll") for (int m = 0; m < 4; ++m)                              \
      _Pragma("unroll") for (int n = 0; n < 4; ++n)                            \
        acc[m][n] = __builtin_amdgcn_mfma_f32_16x16x32_bf16(aF[m], bF[n],      \
                                                            acc[m][n], 0, 0, 0); \
    __builtin_amdgcn_s_setprio(0);                                             \
    _Pragma("unroll") for (int m = 0; m < 4; ++m)                              \
        aF[m] = *(const bf16x8*)(SA_ + aOff[m + 4]);                           \
    if ((T) + 3 < NT) stageB(gB, Bs[ns_], tid, (T) + 3);                       \
    __builtin_amdgcn_s_setprio(1);                                             \
    _Pragma("unroll") for (int m = 0; m < 4; ++m)                              \
      _Pragma("unroll") for (int n = 0; n < 4; ++n)                            \
        acc[m + 4][n] = __builtin_amdgcn_mfma_f32_16x16x32_bf16(aF[m], bF[n],  \
                                                        acc[m + 4][n], 0, 0, 0); \
    __builtin_amdgcn_s_setprio(0);                                             \
  }

  for (int t = 0; t < NT - 2; ++t) KTILE_BODY(t, 8)
  KTILE_BODY(NT - 2, 4)
  KTILE_BODY(NT - 1, 0)
#undef KTILE_BODY

  // Epilogue: C/D layout (16x16x32): col = l&15, row = (l>>4)*4 + reg
  const int gi0 = brow * 256 + wm * 128;
  const int gj0 = bcol * 256 + wn * 64;
  const int lr = (l >> 4) << 2;
  const int lc = l & 15;

#pragma unroll
  for (int m = 0; m < 8; ++m) {
    float hs[4];
#pragma unroll
    for (int r = 0; r < 4; ++r) hs[r] = hsq[gi0 + m * 16 + lr + r];
    float rs[4] = {0.f, 0.f, 0.f, 0.f};
#pragma unroll
    for (int n = 0; n < 4; ++n) {
      const int gj = gj0 + n * 16 + lc;
      const float cs = csq[gj];
#pragma unroll
      for (int r = 0; r < 4; ++r) {
        float d2 = hs[r] + cs - 2.0f * acc[m][n][r];
        d2 = fmaxf(d2, 0.0f);
        const float qv = 1.0f / (1.0f + d2);
        rs[r] += qv;
        if (gj < K_CENT)
          out[(size_t)(gi0 + m * 16 + lr + r) * K_CENT + gj] = qv;
      }
    }
#pragma unroll
    for (int r = 0; r < 4; ++r) {
      float v = rs[r];
      v += __shfl_xor(v, 1);
      v += __shfl_xor(v, 2);
      v += __shfl_xor(v, 4);
      v += __shfl_xor(v, 8);
      if (lc == 0) atomicAdd(&rowsum[gi0 + m * 16 + lr + r], v);
    }
  }
}

// ---------------- normalization ----------------

__global__ __launch_bounds__(256) void norm_k(float* __restrict__ out,
                                              const float* __restrict__ rowsum) {
  const int row = blockIdx.x;
  const int t = threadIdx.x;
  if (t < 250) {  // 1000 floats = 250 float4 per row
    const float inv = 1.0f / rowsum[row];
    float4* p = reinterpret_cast<float4*>(out) + (size_t)row * 250 + t;
    float4 v = *p;
    v.x *= inv; v.y *= inv; v.z *= inv; v.w *= inv;
    *p = v;
  }
}

// ---------------- launch ----------------

extern "C" void kernel_launch(void* const* d_in, const int* in_sizes, int n_in,
                              void* d_out, int out_size, void* d_ws, size_t ws_size,
                              hipStream_t stream) {
  const float* h   = (const float*)d_in[0];
  const float* cen = (const float*)d_in[1];
  float* out = (float*)d_out;
  char* ws = (char*)d_ws;

  u16*   cb     = (u16*)(ws);                           // 2 MB
  u16*   hb     = (u16*)(ws + 2097152);                 // 64 MB
  float* hsq    = (float*)(ws + 2097152 + 67108864);    // 128 KB
  float* csq    = (float*)(ws + 2097152 + 67108864 + 131072);   // 4 KB
  float* rowsum = (float*)(ws + 2097152 + 67108864 + 131072 + 4096); // 128 KB

  prep_c<<<KP, 256, 0, stream>>>(cen, cb, csq);
  prep_h<<<N_ROWS, 256, 0, stream>>>(h, hb, hsq, rowsum);
  gemm_q<<<(N_ROWS / 256) * (KP / 256), 512, 0, stream>>>(hb, cb, hsq, csq, out, rowsum);
  norm_k<<<N_ROWS, 256, 0, stream>>>(out, rowsum);
}